// Round 3
// baseline (4546.963 us; speedup 1.0000x reference)
//
#include <hip/hip_runtime.h>
#include <hip/hip_bf16.h>
#include <math.h>

#define NN 100000
#define NE 800000
#define NG 2048
#define DD 64
#define NR 5
#define TN 128          // nodes per transform block
#define NB ((NN + 255) / 256)   // scan blocks = 391

static __device__ __forceinline__ float sigmoidf_(float x) { return 1.0f / (1.0f + expf(-x)); }

// W[r] = sum_b att[r,b] * basis[b]   -> [5,64,64]
__global__ void k_w(const float* __restrict__ att, const float* __restrict__ basis,
                    float* __restrict__ W) {
    int i = blockIdx.x * blockDim.x + threadIdx.x;
    if (i >= NR * DD * DD) return;
    int r = i >> 12;
    int de = i & 4095;
    float a = 0.f;
#pragma unroll
    for (int b = 0; b < NR; ++b) a += att[r * NR + b] * basis[b * 4096 + de];
    W[i] = a;
}

// in-degree count (int)
__global__ void k_cnt(const int* __restrict__ dst, int* __restrict__ deg) {
    int e = blockIdx.x * blockDim.x + threadIdx.x;
    if (e < NE) atomicAdd(&deg[dst[e]], 1);
}

// block-local exclusive scan of deg; emits per-block totals
__global__ void k_scan1(const int* __restrict__ deg, int* __restrict__ part,
                        int* __restrict__ bsum) {
    __shared__ int s[256];
    int tid = threadIdx.x;
    int i = blockIdx.x * 256 + tid;
    int v = (i < NN) ? deg[i] : 0;
    s[tid] = v;
    __syncthreads();
    for (int off = 1; off < 256; off <<= 1) {
        int t = (tid >= off) ? s[tid - off] : 0;
        __syncthreads();
        s[tid] += t;
        __syncthreads();
    }
    if (i < NN) part[i] = s[tid] - v;   // exclusive within block
    if (tid == 255) bsum[blockIdx.x] = s[255];
}

// scan the 391 block sums (single block)
__global__ void k_scan2(int* __restrict__ bsum) {
    __shared__ int s[512];
    int tid = threadIdx.x;
    int v = (tid < NB) ? bsum[tid] : 0;
    s[tid] = v;
    __syncthreads();
    for (int off = 1; off < 512; off <<= 1) {
        int t = (tid >= off) ? s[tid - off] : 0;
        __syncthreads();
        s[tid] += t;
        __syncthreads();
    }
    if (tid < NB) bsum[tid] = s[tid] - v;  // exclusive
}

// rowptr = part + bsum[block]; invc = 1/max(deg,1); rowptr[NN] = NE
__global__ void k_scan3(const int* __restrict__ part, const int* __restrict__ bsum,
                        const int* __restrict__ deg, int* __restrict__ rowptr,
                        float* __restrict__ invc) {
    int i = blockIdx.x * blockDim.x + threadIdx.x;
    if (i >= NN) return;
    rowptr[i] = part[i] + bsum[i >> 8];
    invc[i] = 1.0f / fmaxf((float)deg[i], 1.0f);
    if (i == 0) rowptr[NN] = NE;
}

// fill CSR: eidx[pos] = src | (type<<20)
__global__ void k_fill(const int* __restrict__ src, const int* __restrict__ dst,
                       const int* __restrict__ et, int* __restrict__ cur,
                       int* __restrict__ eidx) {
    int e = blockIdx.x * blockDim.x + threadIdx.x;
    if (e >= NE) return;
    int d = dst[e];
    int pos = atomicAdd(&cur[d], 1);
    eidx[pos] = src[e] | (et[e] << 20);
}

// segment starts: seg[g] = lower_bound(batch, g)
__global__ void k_seg(const int* __restrict__ batch, int* __restrict__ seg) {
    int g = blockIdx.x * blockDim.x + threadIdx.x;
    if (g > NG) return;
    int lo = 0, hi = NN;
    while (lo < hi) {
        int mid = (lo + hi) >> 1;
        if (batch[mid] < g) lo = mid + 1; else hi = mid;
    }
    seg[g] = lo;
}

// h = relu(x @ lin0_w + lin0_b)
__global__ void k_lin0(const float* __restrict__ x, const float* __restrict__ w,
                       const float* __restrict__ b, float* __restrict__ h) {
    int lane = threadIdx.x & 63, wave = threadIdx.x >> 6;
    float Wc[15];
#pragma unroll
    for (int k = 0; k < 15; ++k) Wc[k] = w[k * DD + lane];
    float bias = b[lane];
    int n0 = blockIdx.x * 256;
    int n1 = min(n0 + 256, NN);
    for (int n = n0 + wave; n < n1; n += 4) {
        int nu = __builtin_amdgcn_readfirstlane(n);
        const float* xr = x + (size_t)nu * 15;
        float a = bias;
#pragma unroll
        for (int k = 0; k < 15; ++k) a += xr[k] * Wc[k];
        h[(size_t)nu * DD + lane] = fmaxf(a, 0.f);
    }
}

// LDS-tiled transform: 128-node tile staged once, 6 GEMMs (5 rel + root) over it.
// r<5 -> hrel[r]; r==5 -> agg (= h@root, seeds aggregation).
__global__ void __launch_bounds__(256) k_transform(
        const float* __restrict__ h, const float* __restrict__ W5,
        const float* __restrict__ root, float* __restrict__ hrel,
        float* __restrict__ agg) {
    __shared__ float hs[TN][DD + 4];   // stride 68 floats: 16B-aligned rows
    __shared__ float ws[DD][DD];
    int tid = threadIdx.x;
    int n0 = blockIdx.x * TN;
    // stage h tile (zero-fill OOB)
    for (int i = tid; i < TN * DD / 4; i += 256) {
        int row = i >> 4, c4 = i & 15;
        float4 v = make_float4(0.f, 0.f, 0.f, 0.f);
        int n = n0 + row;
        if (n < NN) v = ((const float4*)(h + (size_t)n * DD))[c4];
        *(float4*)&hs[row][c4 * 4] = v;
    }
    int cg = tid & 15;        // col group: cols cg*4..+3
    int ng = tid >> 4;        // node group: rows ng + 16*i
    for (int r = 0; r < 6; ++r) {
        const float* Wm = (r < NR) ? (W5 + r * 4096) : root;
        __syncthreads();                         // hs ready / ws safe to overwrite
        for (int i = tid; i < 1024; i += 256)
            ((float4*)ws)[i] = ((const float4*)Wm)[i];
        __syncthreads();
        float acc[8][4];
#pragma unroll
        for (int i = 0; i < 8; ++i)
#pragma unroll
            for (int j = 0; j < 4; ++j) acc[i][j] = 0.f;
#pragma unroll
        for (int k = 0; k < DD; k += 4) {
            float4 b0 = *(float4*)&ws[k + 0][cg * 4];
            float4 b1 = *(float4*)&ws[k + 1][cg * 4];
            float4 b2 = *(float4*)&ws[k + 2][cg * 4];
            float4 b3 = *(float4*)&ws[k + 3][cg * 4];
#pragma unroll
            for (int i = 0; i < 8; ++i) {
                float4 a = *(float4*)&hs[ng + 16 * i][k];
                acc[i][0] += a.x * b0.x + a.y * b1.x + a.z * b2.x + a.w * b3.x;
                acc[i][1] += a.x * b0.y + a.y * b1.y + a.z * b2.y + a.w * b3.y;
                acc[i][2] += a.x * b0.z + a.y * b1.z + a.z * b2.z + a.w * b3.z;
                acc[i][3] += a.x * b0.w + a.y * b1.w + a.z * b2.w + a.w * b3.w;
            }
        }
        float* out = (r < NR) ? (hrel + (size_t)r * NN * DD) : agg;
#pragma unroll
        for (int i = 0; i < 8; ++i) {
            int n = n0 + ng + 16 * i;
            if (n < NN)
                *(float4*)&out[(size_t)n * DD + cg * 4] =
                    make_float4(acc[i][0], acc[i][1], acc[i][2], acc[i][3]);
        }
    }
}

// one wave per node: h[n] = relu(agg[n] + invc[n]*sum_e hrel[et][src] + bias)
__global__ void k_gather(const float* __restrict__ hrel, const int* __restrict__ eidx,
                         const int* __restrict__ rowptr, const float* __restrict__ invc,
                         const float* __restrict__ agg, const float* __restrict__ bias,
                         float* __restrict__ h) {
    int gw = (blockIdx.x * blockDim.x + threadIdx.x) >> 6;
    int lane = threadIdx.x & 63;
    if (gw >= NN) return;
    int n = __builtin_amdgcn_readfirstlane(gw);
    int r0 = rowptr[n], r1 = rowptr[n + 1];
    float acc = 0.f;
    for (int base = r0; base < r1; base += 64) {
        int idx = base + lane;
        int p = (idx < r1) ? eidx[idx] : 0;
        int cnt = min(r1 - base, 64);
        for (int i = 0; i < cnt; ++i) {
            int pp = __shfl(p, i, 64);
            int s = pp & 0xFFFFF;
            int t = pp >> 20;
            acc += hrel[((size_t)t * NN + s) * DD + lane];
        }
    }
    float rootv = agg[(size_t)n * DD + lane];
    h[(size_t)n * DD + lane] = fmaxf(rootv + invc[n] * acc + bias[lane], 0.f);
}

// LSTM cell: block per graph, 64 threads
__global__ void k_lstm(const float* __restrict__ qstar, float* __restrict__ hx,
                       float* __restrict__ cx, const float* __restrict__ wih,
                       const float* __restrict__ whh, const float* __restrict__ bih,
                       const float* __restrict__ bhh) {
    int g = blockIdx.x;
    int j = threadIdx.x;
    float acc[4];
#pragma unroll
    for (int q = 0; q < 4; ++q) acc[q] = bih[q * DD + j] + bhh[q * DD + j];
    const float4* q4 = (const float4*)(qstar + (size_t)g * 2 * DD);
#pragma unroll 8
    for (int k4 = 0; k4 < 32; ++k4) {
        float4 qv = q4[k4];
#pragma unroll
        for (int q = 0; q < 4; ++q) {
            float4 wv = ((const float4*)(wih + (size_t)(q * DD + j) * 2 * DD))[k4];
            acc[q] += qv.x * wv.x + qv.y * wv.y + qv.z * wv.z + qv.w * wv.w;
        }
    }
    const float4* h4 = (const float4*)(hx + (size_t)g * DD);
#pragma unroll 4
    for (int k4 = 0; k4 < 16; ++k4) {
        float4 hv = h4[k4];
#pragma unroll
        for (int q = 0; q < 4; ++q) {
            float4 wv = ((const float4*)(whh + (size_t)(q * DD + j) * DD))[k4];
            acc[q] += hv.x * wv.x + hv.y * wv.y + hv.z * wv.z + hv.w * wv.w;
        }
    }
    float c_old = cx[(size_t)g * DD + j];
    __syncthreads();
    float iv = sigmoidf_(acc[0]);
    float fv = sigmoidf_(acc[1]);
    float gv = tanhf(acc[2]);
    float ov = sigmoidf_(acc[3]);
    float c = fv * c_old + iv * gv;
    cx[(size_t)g * DD + j] = c;
    hx[(size_t)g * DD + j] = ov * tanhf(c);
}

// per-graph segment softmax + weighted sum; writes q_star = [q, r]
__global__ void k_attn(const float* __restrict__ h, const int* __restrict__ seg,
                       const float* __restrict__ hx, float* __restrict__ qstar,
                       float* __restrict__ esc) {
    int g = blockIdx.x;
    int lane = threadIdx.x & 63, wave = threadIdx.x >> 6;
    int s0 = seg[g], s1 = seg[g + 1];
    float q = hx[(size_t)g * DD + lane];
    __shared__ float lmax[4];
    __shared__ float lsum[4];
    __shared__ float lred[4][64];
    float mymax = -INFINITY;
    for (int n = s0 + wave; n < s1; n += 4) {
        float v = h[(size_t)n * DD + lane] * q;
#pragma unroll
        for (int off = 32; off >= 1; off >>= 1) v += __shfl_xor(v, off, 64);
        if (lane == 0) esc[n] = v;
        mymax = fmaxf(mymax, v);
    }
    if (lane == 0) lmax[wave] = mymax;
    __syncthreads();
    float m = fmaxf(fmaxf(lmax[0], lmax[1]), fmaxf(lmax[2], lmax[3]));
    float racc = 0.f, sacc = 0.f;
    for (int n = s0 + wave; n < s1; n += 4) {
        float a = expf(esc[n] - m);
        racc += a * h[(size_t)n * DD + lane];
        sacc += a;
    }
    lred[wave][lane] = racc;
    if (lane == 0) lsum[wave] = sacc;
    __syncthreads();
    if (wave == 0) {
        float r = lred[0][lane] + lred[1][lane] + lred[2][lane] + lred[3][lane];
        float s = lsum[0] + lsum[1] + lsum[2] + lsum[3];
        qstar[(size_t)g * 2 * DD + lane] = q;
        qstar[(size_t)g * 2 * DD + DD + lane] = (s > 0.f) ? (r / s) : 0.f;
    }
}

// out = relu(q_star @ lin1 + b1) @ lin2 + b2
__global__ void k_final(const float* __restrict__ qstar, const float* __restrict__ w1,
                        const float* __restrict__ b1, const float* __restrict__ w2,
                        const float* __restrict__ b2, float* __restrict__ out) {
    int g = blockIdx.x;
    int j = threadIdx.x;
    float a = b1[j];
    const float* qs = qstar + (size_t)g * 2 * DD;
#pragma unroll 16
    for (int k = 0; k < 2 * DD; ++k) a += qs[k] * w1[k * DD + j];
    float t = fmaxf(a, 0.f);
    __shared__ float ts[64];
    ts[j] = t;
    __syncthreads();
    if (j < 12) {
        float o = b2[j];
#pragma unroll 16
        for (int d = 0; d < DD; ++d) o += ts[d] * w2[d * 12 + j];
        out[(size_t)g * 12 + j] = o;
    }
}

extern "C" void kernel_launch(void* const* d_in, const int* in_sizes, int n_in,
                              void* d_out, int out_size, void* d_ws, size_t ws_size,
                              hipStream_t stream) {
    const float* x     = (const float*)d_in[0];
    const int*   ei    = (const int*)d_in[1];
    const int*   etype = (const int*)d_in[2];
    const int*   batch = (const int*)d_in[3];
    const float* l0w   = (const float*)d_in[4];
    const float* l0b   = (const float*)d_in[5];
    const float* basis = (const float*)d_in[6];
    const float* att   = (const float*)d_in[7];
    const float* root  = (const float*)d_in[8];
    const float* convb = (const float*)d_in[9];
    const float* wih   = (const float*)d_in[10];
    const float* whh   = (const float*)d_in[11];
    const float* bih   = (const float*)d_in[12];
    const float* bhh   = (const float*)d_in[13];
    const float* l1w   = (const float*)d_in[14];
    const float* l1b   = (const float*)d_in[15];
    const float* l2w   = (const float*)d_in[16];
    const float* l2b   = (const float*)d_in[17];
    const int* src = ei;
    const int* dst = ei + NE;
    float* out = (float*)d_out;

    char* ws = (char*)d_ws;
    size_t off = 0;
    auto alloc = [&](size_t bytes) {
        void* p = ws + off;
        off = (off + bytes + 255) & ~(size_t)255;
        return p;
    };
    float* W5     = (float*)alloc((size_t)NR * DD * DD * 4);
    float* h      = (float*)alloc((size_t)NN * DD * 4);
    float* agg    = (float*)alloc((size_t)NN * DD * 4);
    float* hrel   = (float*)alloc((size_t)NR * NN * DD * 4);
    int*   deg    = (int*)alloc((size_t)NN * 4);
    float* invc   = (float*)alloc((size_t)NN * 4);
    int*   part   = (int*)alloc((size_t)NN * 4);
    int*   bsum   = (int*)alloc((size_t)512 * 4);
    int*   rowptr = (int*)alloc((size_t)(NN + 1) * 4);
    int*   cur    = (int*)alloc((size_t)NN * 4);
    int*   eidx   = (int*)alloc((size_t)NE * 4);
    float* esc    = (float*)alloc((size_t)NN * 4);
    int*   seg    = (int*)alloc((size_t)(NG + 1) * 4);
    float* qstar  = (float*)alloc((size_t)NG * 2 * DD * 4);
    float* hx     = (float*)alloc((size_t)NG * DD * 4);
    float* cx     = (float*)alloc((size_t)NG * DD * 4);

    hipMemsetAsync(deg, 0, (size_t)NN * 4, stream);
    hipMemsetAsync(qstar, 0, (size_t)NG * 2 * DD * 4, stream);
    hipMemsetAsync(hx, 0, (size_t)NG * DD * 4, stream);
    hipMemsetAsync(cx, 0, (size_t)NG * DD * 4, stream);

    // CSR build
    k_cnt<<<(NE + 255) / 256, 256, 0, stream>>>(dst, deg);
    k_scan1<<<NB, 256, 0, stream>>>(deg, part, bsum);
    k_scan2<<<1, 512, 0, stream>>>(bsum);
    k_scan3<<<(NN + 255) / 256, 256, 0, stream>>>(part, bsum, deg, rowptr, invc);
    hipMemcpyAsync(cur, rowptr, (size_t)NN * 4, hipMemcpyDeviceToDevice, stream);
    k_fill<<<(NE + 255) / 256, 256, 0, stream>>>(src, dst, etype, cur, eidx);

    k_w<<<(NR * DD * DD + 255) / 256, 256, 0, stream>>>(att, basis, W5);
    k_seg<<<(NG + 256) / 256, 256, 0, stream>>>(batch, seg);
    k_lin0<<<(NN + 255) / 256, 256, 0, stream>>>(x, l0w, l0b, h);

    for (int s = 0; s < 6; ++s) {
        k_transform<<<(NN + TN - 1) / TN, 256, 0, stream>>>(h, W5, root, hrel, agg);
        k_gather<<<(NN * 64 + 255) / 256, 256, 0, stream>>>(hrel, eidx, rowptr, invc,
                                                            agg, convb, h);
    }

    for (int t = 0; t < 6; ++t) {
        k_lstm<<<NG, 64, 0, stream>>>(qstar, hx, cx, wih, whh, bih, bhh);
        k_attn<<<NG, 256, 0, stream>>>(h, seg, hx, qstar, esc);
    }

    k_final<<<NG, 64, 0, stream>>>(qstar, l1w, l1b, l2w, l2b, out);
}

// Round 4
// 1539.752 us; speedup vs baseline: 2.9530x; 2.9530x over previous
//
#include <hip/hip_runtime.h>
#include <hip/hip_bf16.h>
#include <math.h>

#define NN 100000
#define NE 800000
#define NG 2048
#define DD 64
#define NR 5
#define KK 384          // 6 * 64 (5 relations + root)
#define NB ((NN + 255) / 256)   // scan blocks = 391

static __device__ __forceinline__ float sigmoidf_(float x) { return 1.0f / (1.0f + expf(-x)); }

// Wcat[t][k][c]: t<5 = sum_b att[t,b]*basis[b];  t==5 = root.  -> [6,64,64]
__global__ void k_w(const float* __restrict__ att, const float* __restrict__ basis,
                    const float* __restrict__ root, float* __restrict__ Wcat) {
    int i = blockIdx.x * blockDim.x + threadIdx.x;
    if (i >= 6 * DD * DD) return;
    int t = i >> 12;
    int de = i & 4095;
    float a;
    if (t < NR) {
        a = 0.f;
#pragma unroll
        for (int b = 0; b < NR; ++b) a += att[t * NR + b] * basis[b * 4096 + de];
    } else {
        a = root[de];
    }
    Wcat[i] = a;
}

// in-degree count (int)
__global__ void k_cnt(const int* __restrict__ dst, int* __restrict__ deg) {
    int e = blockIdx.x * blockDim.x + threadIdx.x;
    if (e < NE) atomicAdd(&deg[dst[e]], 1);
}

// block-local exclusive scan of deg; emits per-block totals
__global__ void k_scan1(const int* __restrict__ deg, int* __restrict__ part,
                        int* __restrict__ bsum) {
    __shared__ int s[256];
    int tid = threadIdx.x;
    int i = blockIdx.x * 256 + tid;
    int v = (i < NN) ? deg[i] : 0;
    s[tid] = v;
    __syncthreads();
    for (int off = 1; off < 256; off <<= 1) {
        int t = (tid >= off) ? s[tid - off] : 0;
        __syncthreads();
        s[tid] += t;
        __syncthreads();
    }
    if (i < NN) part[i] = s[tid] - v;
    if (tid == 255) bsum[blockIdx.x] = s[255];
}

__global__ void k_scan2(int* __restrict__ bsum) {
    __shared__ int s[512];
    int tid = threadIdx.x;
    int v = (tid < NB) ? bsum[tid] : 0;
    s[tid] = v;
    __syncthreads();
    for (int off = 1; off < 512; off <<= 1) {
        int t = (tid >= off) ? s[tid - off] : 0;
        __syncthreads();
        s[tid] += t;
        __syncthreads();
    }
    if (tid < NB) bsum[tid] = s[tid] - v;
}

__global__ void k_scan3(const int* __restrict__ part, const int* __restrict__ bsum,
                        const int* __restrict__ deg, int* __restrict__ rowptr,
                        float* __restrict__ invc) {
    int i = blockIdx.x * blockDim.x + threadIdx.x;
    if (i >= NN) return;
    rowptr[i] = part[i] + bsum[i >> 8];
    invc[i] = 1.0f / fmaxf((float)deg[i], 1.0f);
    if (i == 0) rowptr[NN] = NE;
}

// fill CSR: eidx[pos] = src | (type<<20)
__global__ void k_fill(const int* __restrict__ src, const int* __restrict__ dst,
                       const int* __restrict__ et, int* __restrict__ cur,
                       int* __restrict__ eidx) {
    int e = blockIdx.x * blockDim.x + threadIdx.x;
    if (e >= NE) return;
    int d = dst[e];
    int pos = atomicAdd(&cur[d], 1);
    eidx[pos] = src[e] | (et[e] << 20);
}

// segment starts: seg[g] = lower_bound(batch, g)
__global__ void k_seg(const int* __restrict__ batch, int* __restrict__ seg) {
    int g = blockIdx.x * blockDim.x + threadIdx.x;
    if (g > NG) return;
    int lo = 0, hi = NN;
    while (lo < hi) {
        int mid = (lo + hi) >> 1;
        if (batch[mid] < g) lo = mid + 1; else hi = mid;
    }
    seg[g] = lo;
}

// h = relu(x @ lin0_w + lin0_b)
__global__ void k_lin0(const float* __restrict__ x, const float* __restrict__ w,
                       const float* __restrict__ b, float* __restrict__ h) {
    int lane = threadIdx.x & 63, wave = threadIdx.x >> 6;
    float Wc[15];
#pragma unroll
    for (int k = 0; k < 15; ++k) Wc[k] = w[k * DD + lane];
    float bias = b[lane];
    int n0 = blockIdx.x * 256;
    int n1 = min(n0 + 256, NN);
    for (int n = n0 + wave; n < n1; n += 4) {
        int nu = __builtin_amdgcn_readfirstlane(n);
        const float* xr = x + (size_t)nu * 15;
        float a = bias;
#pragma unroll
        for (int k = 0; k < 15; ++k) a += xr[k] * Wc[k];
        h[(size_t)nu * DD + lane] = fmaxf(a, 0.f);
    }
}

// Phase 1: wave per dst node. Accumulate per-relation h-space sums in registers,
// write scat[n][0..319] = invc * s_t, scat[n][320..383] = h[n] (root slot).
__global__ void k_gather2(const float* __restrict__ h, const int* __restrict__ eidx,
                          const int* __restrict__ rowptr, const float* __restrict__ invc,
                          float* __restrict__ scat) {
    int gw = (blockIdx.x * blockDim.x + threadIdx.x) >> 6;
    int lane = threadIdx.x & 63;
    if (gw >= NN) return;
    int n = __builtin_amdgcn_readfirstlane(gw);
    int r0 = rowptr[n], r1 = rowptr[n + 1];
    float a0 = 0.f, a1 = 0.f, a2 = 0.f, a3 = 0.f, a4 = 0.f;
    for (int base = r0; base < r1; base += 64) {
        int idx = base + lane;
        int p = (idx < r1) ? eidx[idx] : 0;
        int cnt = min(r1 - base, 64);
        for (int i = 0; i < cnt; ++i) {
            int pp = __shfl(p, i, 64);
            int s = pp & 0xFFFFF;
            int t = pp >> 20;
            float v = h[(size_t)s * DD + lane];
            a0 += (t == 0) ? v : 0.f;
            a1 += (t == 1) ? v : 0.f;
            a2 += (t == 2) ? v : 0.f;
            a3 += (t == 3) ? v : 0.f;
            a4 += (t == 4) ? v : 0.f;
        }
    }
    float ic = invc[n];
    float* row = scat + (size_t)n * KK;
    row[0 * DD + lane] = a0 * ic;
    row[1 * DD + lane] = a1 * ic;
    row[2 * DD + lane] = a2 * ic;
    row[3 * DD + lane] = a3 * ic;
    row[4 * DD + lane] = a4 * ic;
    row[5 * DD + lane] = h[(size_t)n * DD + lane];
}

// Phase 2: h' = relu(scat[NN x 384] @ Wcat[384 x 64] + bias)
// Tile: 64 nodes x 64 cols per block, K-chunks of 64. 16 acc/thread.
__global__ void __launch_bounds__(256, 4) k_trans2(
        const float* __restrict__ scat, const float* __restrict__ Wcat,
        const float* __restrict__ bias, float* __restrict__ h) {
    __shared__ float As[64][68];
    __shared__ float Bs[64][64];
    int tid = threadIdx.x;
    int n0 = blockIdx.x * 64;
    int c4 = tid & 15;       // col group: cols c4*4..+3
    int n4g = tid >> 4;      // node group: nodes n4g*4..+3
    float acc[4][4];
#pragma unroll
    for (int j = 0; j < 4; ++j)
#pragma unroll
        for (int c = 0; c < 4; ++c) acc[j][c] = 0.f;

    for (int kc = 0; kc < 6; ++kc) {
        __syncthreads();   // protect previous chunk's LDS reads
        // stage A: 64 rows x 64 k-floats
        for (int i = tid; i < 64 * 16; i += 256) {
            int row = i >> 4, cg = i & 15;
            float4 v = make_float4(0.f, 0.f, 0.f, 0.f);
            if (n0 + row < NN)
                v = *(const float4*)(scat + (size_t)(n0 + row) * KK + kc * 64 + cg * 4);
            *(float4*)&As[row][cg * 4] = v;
        }
        // stage B: Wcat rows kc*64 .. +63
        for (int i = tid; i < 1024; i += 256)
            ((float4*)Bs)[i] = ((const float4*)(Wcat + kc * 64 * DD))[i];
        __syncthreads();
#pragma unroll 4
        for (int k = 0; k < 64; k += 4) {
            float4 b0 = *(float4*)&Bs[k + 0][c4 * 4];
            float4 b1 = *(float4*)&Bs[k + 1][c4 * 4];
            float4 b2 = *(float4*)&Bs[k + 2][c4 * 4];
            float4 b3 = *(float4*)&Bs[k + 3][c4 * 4];
#pragma unroll
            for (int j = 0; j < 4; ++j) {
                float4 a = *(float4*)&As[n4g * 4 + j][k];
                acc[j][0] += a.x * b0.x + a.y * b1.x + a.z * b2.x + a.w * b3.x;
                acc[j][1] += a.x * b0.y + a.y * b1.y + a.z * b2.y + a.w * b3.y;
                acc[j][2] += a.x * b0.z + a.y * b1.z + a.z * b2.z + a.w * b3.z;
                acc[j][3] += a.x * b0.w + a.y * b1.w + a.z * b2.w + a.w * b3.w;
            }
        }
    }
#pragma unroll
    for (int j = 0; j < 4; ++j) {
        int n = n0 + n4g * 4 + j;
        if (n < NN) {
            float4 o;
            o.x = fmaxf(acc[j][0] + bias[c4 * 4 + 0], 0.f);
            o.y = fmaxf(acc[j][1] + bias[c4 * 4 + 1], 0.f);
            o.z = fmaxf(acc[j][2] + bias[c4 * 4 + 2], 0.f);
            o.w = fmaxf(acc[j][3] + bias[c4 * 4 + 3], 0.f);
            *(float4*)&h[(size_t)n * DD + c4 * 4] = o;
        }
    }
}

// LSTM cell: block per graph, 64 threads
__global__ void k_lstm(const float* __restrict__ qstar, float* __restrict__ hx,
                       float* __restrict__ cx, const float* __restrict__ wih,
                       const float* __restrict__ whh, const float* __restrict__ bih,
                       const float* __restrict__ bhh) {
    int g = blockIdx.x;
    int j = threadIdx.x;
    float acc[4];
#pragma unroll
    for (int q = 0; q < 4; ++q) acc[q] = bih[q * DD + j] + bhh[q * DD + j];
    const float4* q4 = (const float4*)(qstar + (size_t)g * 2 * DD);
#pragma unroll 8
    for (int k4 = 0; k4 < 32; ++k4) {
        float4 qv = q4[k4];
#pragma unroll
        for (int q = 0; q < 4; ++q) {
            float4 wv = ((const float4*)(wih + (size_t)(q * DD + j) * 2 * DD))[k4];
            acc[q] += qv.x * wv.x + qv.y * wv.y + qv.z * wv.z + qv.w * wv.w;
        }
    }
    const float4* h4 = (const float4*)(hx + (size_t)g * DD);
#pragma unroll 4
    for (int k4 = 0; k4 < 16; ++k4) {
        float4 hv = h4[k4];
#pragma unroll
        for (int q = 0; q < 4; ++q) {
            float4 wv = ((const float4*)(whh + (size_t)(q * DD + j) * DD))[k4];
            acc[q] += hv.x * wv.x + hv.y * wv.y + hv.z * wv.z + hv.w * wv.w;
        }
    }
    float c_old = cx[(size_t)g * DD + j];
    __syncthreads();
    float iv = sigmoidf_(acc[0]);
    float fv = sigmoidf_(acc[1]);
    float gv = tanhf(acc[2]);
    float ov = sigmoidf_(acc[3]);
    float c = fv * c_old + iv * gv;
    cx[(size_t)g * DD + j] = c;
    hx[(size_t)g * DD + j] = ov * tanhf(c);
}

// per-graph segment softmax + weighted sum; writes q_star = [q, r]
__global__ void k_attn(const float* __restrict__ h, const int* __restrict__ seg,
                       const float* __restrict__ hx, float* __restrict__ qstar,
                       float* __restrict__ esc) {
    int g = blockIdx.x;
    int lane = threadIdx.x & 63, wave = threadIdx.x >> 6;
    int s0 = seg[g], s1 = seg[g + 1];
    float q = hx[(size_t)g * DD + lane];
    __shared__ float lmax[4];
    __shared__ float lsum[4];
    __shared__ float lred[4][64];
    float mymax = -INFINITY;
    for (int n = s0 + wave; n < s1; n += 4) {
        float v = h[(size_t)n * DD + lane] * q;
#pragma unroll
        for (int off = 32; off >= 1; off >>= 1) v += __shfl_xor(v, off, 64);
        if (lane == 0) esc[n] = v;
        mymax = fmaxf(mymax, v);
    }
    if (lane == 0) lmax[wave] = mymax;
    __syncthreads();
    float m = fmaxf(fmaxf(lmax[0], lmax[1]), fmaxf(lmax[2], lmax[3]));
    float racc = 0.f, sacc = 0.f;
    for (int n = s0 + wave; n < s1; n += 4) {
        float a = expf(esc[n] - m);
        racc += a * h[(size_t)n * DD + lane];
        sacc += a;
    }
    lred[wave][lane] = racc;
    if (lane == 0) lsum[wave] = sacc;
    __syncthreads();
    if (wave == 0) {
        float r = lred[0][lane] + lred[1][lane] + lred[2][lane] + lred[3][lane];
        float s = lsum[0] + lsum[1] + lsum[2] + lsum[3];
        qstar[(size_t)g * 2 * DD + lane] = q;
        qstar[(size_t)g * 2 * DD + DD + lane] = (s > 0.f) ? (r / s) : 0.f;
    }
}

// out = relu(q_star @ lin1 + b1) @ lin2 + b2
__global__ void k_final(const float* __restrict__ qstar, const float* __restrict__ w1,
                        const float* __restrict__ b1, const float* __restrict__ w2,
                        const float* __restrict__ b2, float* __restrict__ out) {
    int g = blockIdx.x;
    int j = threadIdx.x;
    float a = b1[j];
    const float* qs = qstar + (size_t)g * 2 * DD;
#pragma unroll 16
    for (int k = 0; k < 2 * DD; ++k) a += qs[k] * w1[k * DD + j];
    float t = fmaxf(a, 0.f);
    __shared__ float ts[64];
    ts[j] = t;
    __syncthreads();
    if (j < 12) {
        float o = b2[j];
#pragma unroll 16
        for (int d = 0; d < DD; ++d) o += ts[d] * w2[d * 12 + j];
        out[(size_t)g * 12 + j] = o;
    }
}

extern "C" void kernel_launch(void* const* d_in, const int* in_sizes, int n_in,
                              void* d_out, int out_size, void* d_ws, size_t ws_size,
                              hipStream_t stream) {
    const float* x     = (const float*)d_in[0];
    const int*   ei    = (const int*)d_in[1];
    const int*   etype = (const int*)d_in[2];
    const int*   batch = (const int*)d_in[3];
    const float* l0w   = (const float*)d_in[4];
    const float* l0b   = (const float*)d_in[5];
    const float* basis = (const float*)d_in[6];
    const float* att   = (const float*)d_in[7];
    const float* root  = (const float*)d_in[8];
    const float* convb = (const float*)d_in[9];
    const float* wih   = (const float*)d_in[10];
    const float* whh   = (const float*)d_in[11];
    const float* bih   = (const float*)d_in[12];
    const float* bhh   = (const float*)d_in[13];
    const float* l1w   = (const float*)d_in[14];
    const float* l1b   = (const float*)d_in[15];
    const float* l2w   = (const float*)d_in[16];
    const float* l2b   = (const float*)d_in[17];
    const int* src = ei;
    const int* dst = ei + NE;
    float* out = (float*)d_out;

    char* ws = (char*)d_ws;
    size_t off = 0;
    auto alloc = [&](size_t bytes) {
        void* p = ws + off;
        off = (off + bytes + 255) & ~(size_t)255;
        return p;
    };
    float* Wcat   = (float*)alloc((size_t)6 * DD * DD * 4);
    float* h      = (float*)alloc((size_t)NN * DD * 4);
    float* scat   = (float*)alloc((size_t)NN * KK * 4);
    int*   deg    = (int*)alloc((size_t)NN * 4);
    float* invc   = (float*)alloc((size_t)NN * 4);
    int*   part   = (int*)alloc((size_t)NN * 4);
    int*   bsum   = (int*)alloc((size_t)512 * 4);
    int*   rowptr = (int*)alloc((size_t)(NN + 1) * 4);
    int*   cur    = (int*)alloc((size_t)NN * 4);
    int*   eidx   = (int*)alloc((size_t)NE * 4);
    float* esc    = (float*)alloc((size_t)NN * 4);
    int*   seg    = (int*)alloc((size_t)(NG + 1) * 4);
    float* qstar  = (float*)alloc((size_t)NG * 2 * DD * 4);
    float* hx     = (float*)alloc((size_t)NG * DD * 4);
    float* cx     = (float*)alloc((size_t)NG * DD * 4);

    hipMemsetAsync(deg, 0, (size_t)NN * 4, stream);
    hipMemsetAsync(qstar, 0, (size_t)NG * 2 * DD * 4, stream);
    hipMemsetAsync(hx, 0, (size_t)NG * DD * 4, stream);
    hipMemsetAsync(cx, 0, (size_t)NG * DD * 4, stream);

    // CSR build
    k_cnt<<<(NE + 255) / 256, 256, 0, stream>>>(dst, deg);
    k_scan1<<<NB, 256, 0, stream>>>(deg, part, bsum);
    k_scan2<<<1, 512, 0, stream>>>(bsum);
    k_scan3<<<(NN + 255) / 256, 256, 0, stream>>>(part, bsum, deg, rowptr, invc);
    hipMemcpyAsync(cur, rowptr, (size_t)NN * 4, hipMemcpyDeviceToDevice, stream);
    k_fill<<<(NE + 255) / 256, 256, 0, stream>>>(src, dst, etype, cur, eidx);

    k_w<<<(6 * DD * DD + 255) / 256, 256, 0, stream>>>(att, basis, root, Wcat);
    k_seg<<<(NG + 256) / 256, 256, 0, stream>>>(batch, seg);
    k_lin0<<<(NN + 255) / 256, 256, 0, stream>>>(x, l0w, l0b, h);

    for (int s = 0; s < 6; ++s) {
        k_gather2<<<(NN * 64 + 255) / 256, 256, 0, stream>>>(h, eidx, rowptr, invc, scat);
        k_trans2<<<(NN + 63) / 64, 256, 0, stream>>>(scat, Wcat, convb, h);
    }

    for (int t = 0; t < 6; ++t) {
        k_lstm<<<NG, 64, 0, stream>>>(qstar, hx, cx, wih, whh, bih, bhh);
        k_attn<<<NG, 256, 0, stream>>>(h, seg, hx, qstar, esc);
    }

    k_final<<<NG, 64, 0, stream>>>(qstar, l1w, l1b, l2w, l2b, out);
}

// Round 6
// 1519.602 us; speedup vs baseline: 2.9922x; 1.0133x over previous
//
#include <hip/hip_runtime.h>
#include <hip/hip_bf16.h>
#include <math.h>

#define NN 100000
#define NE 800000
#define NG 2048
#define DD 64
#define NR 5
#define KK 384          // 6 * 64 (5 relations + root)
#define NB ((NN + 255) / 256)   // scan blocks = 391

typedef __attribute__((ext_vector_type(8))) short bf16x8;
typedef __attribute__((ext_vector_type(4))) float f32x4;
typedef unsigned short ushort_t;
typedef unsigned int uint_t;

static __device__ __forceinline__ float sigmoidf_(float x) { return 1.0f / (1.0f + expf(-x)); }

// round-to-nearest-even f32 -> bf16 (values known finite)
static __device__ __forceinline__ ushort_t f2bf(float f) {
    uint_t u = __float_as_uint(f);
    uint_t r = (u + 0x7FFFu + ((u >> 16) & 1u)) >> 16;
    return (ushort_t)r;
}
static __device__ __forceinline__ float bf2f(ushort_t b) {
    return __uint_as_float(((uint_t)b) << 16);
}

// WT[c][k] hi/lo bf16, c in [0,64), k = t*64+kd. t<5: sum_b att[t,b]*basis[b][kd][c]; t==5: root[kd][c].
__global__ void k_w2(const float* __restrict__ att, const float* __restrict__ basis,
                     const float* __restrict__ root, ushort_t* __restrict__ wt_hi,
                     ushort_t* __restrict__ wt_lo) {
    int i = blockIdx.x * blockDim.x + threadIdx.x;
    if (i >= DD * KK) return;
    int c = i / KK;
    int k = i % KK;
    int t = k >> 6;
    int kd = k & 63;
    float w;
    if (t < NR) {
        w = 0.f;
#pragma unroll
        for (int b = 0; b < NR; ++b) w += att[t * NR + b] * basis[(b * DD + kd) * DD + c];
    } else {
        w = root[kd * DD + c];
    }
    ushort_t hi = f2bf(w);
    ushort_t lo = f2bf(w - bf2f(hi));
    wt_hi[c * KK + k] = hi;
    wt_lo[c * KK + k] = lo;
}

// in-degree count (int)
__global__ void k_cnt(const int* __restrict__ dst, int* __restrict__ deg) {
    int e = blockIdx.x * blockDim.x + threadIdx.x;
    if (e < NE) atomicAdd(&deg[dst[e]], 1);
}

// block-local exclusive scan of deg; emits per-block totals
__global__ void k_scan1(const int* __restrict__ deg, int* __restrict__ part,
                        int* __restrict__ bsum) {
    __shared__ int s[256];
    int tid = threadIdx.x;
    int i = blockIdx.x * 256 + tid;
    int v = (i < NN) ? deg[i] : 0;
    s[tid] = v;
    __syncthreads();
    for (int off = 1; off < 256; off <<= 1) {
        int t = (tid >= off) ? s[tid - off] : 0;
        __syncthreads();
        s[tid] += t;
        __syncthreads();
    }
    if (i < NN) part[i] = s[tid] - v;
    if (tid == 255) bsum[blockIdx.x] = s[255];
}

__global__ void k_scan2(int* __restrict__ bsum) {
    __shared__ int s[512];
    int tid = threadIdx.x;
    int v = (tid < NB) ? bsum[tid] : 0;
    s[tid] = v;
    __syncthreads();
    for (int off = 1; off < 512; off <<= 1) {
        int t = (tid >= off) ? s[tid - off] : 0;
        __syncthreads();
        s[tid] += t;
        __syncthreads();
    }
    if (tid < NB) bsum[tid] = s[tid] - v;
}

__global__ void k_scan3(const int* __restrict__ part, const int* __restrict__ bsum,
                        const int* __restrict__ deg, int* __restrict__ rowptr,
                        float* __restrict__ invc) {
    int i = blockIdx.x * blockDim.x + threadIdx.x;
    if (i >= NN) return;
    rowptr[i] = part[i] + bsum[i >> 8];
    invc[i] = 1.0f / fmaxf((float)deg[i], 1.0f);
    if (i == 0) rowptr[NN] = NE;
}

// fill CSR: eidx[pos] = src | (type<<20)
__global__ void k_fill(const int* __restrict__ src, const int* __restrict__ dst,
                       const int* __restrict__ et, int* __restrict__ cur,
                       int* __restrict__ eidx) {
    int e = blockIdx.x * blockDim.x + threadIdx.x;
    if (e >= NE) return;
    int d = dst[e];
    int pos = atomicAdd(&cur[d], 1);
    eidx[pos] = src[e] | (et[e] << 20);
}

// segment starts: seg[g] = lower_bound(batch, g)
__global__ void k_seg(const int* __restrict__ batch, int* __restrict__ seg) {
    int g = blockIdx.x * blockDim.x + threadIdx.x;
    if (g > NG) return;
    int lo = 0, hi = NN;
    while (lo < hi) {
        int mid = (lo + hi) >> 1;
        if (batch[mid] < g) lo = mid + 1; else hi = mid;
    }
    seg[g] = lo;
}

// h = relu(x @ lin0_w + lin0_b)
__global__ void k_lin0(const float* __restrict__ x, const float* __restrict__ w,
                       const float* __restrict__ b, float* __restrict__ h) {
    int lane = threadIdx.x & 63, wave = threadIdx.x >> 6;
    float Wc[15];
#pragma unroll
    for (int k = 0; k < 15; ++k) Wc[k] = w[k * DD + lane];
    float bias = b[lane];
    int n0 = blockIdx.x * 256;
    int n1 = min(n0 + 256, NN);
    for (int n = n0 + wave; n < n1; n += 4) {
        int nu = __builtin_amdgcn_readfirstlane(n);
        const float* xr = x + (size_t)nu * 15;
        float a = bias;
#pragma unroll
        for (int k = 0; k < 15; ++k) a += xr[k] * Wc[k];
        h[(size_t)nu * DD + lane] = fmaxf(a, 0.f);
    }
}

// Phase 1: wave per dst node; per-relation mean sums -> scat bf16 hi/lo planes.
// scat row layout: k = t*64 + d, t in [0,5): invc*sum_t ; t==5: h[n].
__global__ void k_gather3(const float* __restrict__ h, const int* __restrict__ eidx,
                          const int* __restrict__ rowptr, const float* __restrict__ invc,
                          ushort_t* __restrict__ scat_hi, ushort_t* __restrict__ scat_lo) {
    int gw = (blockIdx.x * blockDim.x + threadIdx.x) >> 6;
    int lane = threadIdx.x & 63;
    if (gw >= NN) return;
    int n = __builtin_amdgcn_readfirstlane(gw);
    int r0 = rowptr[n], r1 = rowptr[n + 1];
    float a0 = 0.f, a1 = 0.f, a2 = 0.f, a3 = 0.f, a4 = 0.f;
    int i = r0;
    for (; i + 4 <= r1; i += 4) {
        int p0 = eidx[i + 0], p1 = eidx[i + 1], p2 = eidx[i + 2], p3 = eidx[i + 3];
        float v0 = h[(size_t)(p0 & 0xFFFFF) * DD + lane];
        float v1 = h[(size_t)(p1 & 0xFFFFF) * DD + lane];
        float v2 = h[(size_t)(p2 & 0xFFFFF) * DD + lane];
        float v3 = h[(size_t)(p3 & 0xFFFFF) * DD + lane];
        int t0 = p0 >> 20, t1 = p1 >> 20, t2 = p2 >> 20, t3 = p3 >> 20;
        a0 += (t0 == 0 ? v0 : 0.f) + (t1 == 0 ? v1 : 0.f) + (t2 == 0 ? v2 : 0.f) + (t3 == 0 ? v3 : 0.f);
        a1 += (t0 == 1 ? v0 : 0.f) + (t1 == 1 ? v1 : 0.f) + (t2 == 1 ? v2 : 0.f) + (t3 == 1 ? v3 : 0.f);
        a2 += (t0 == 2 ? v0 : 0.f) + (t1 == 2 ? v1 : 0.f) + (t2 == 2 ? v2 : 0.f) + (t3 == 2 ? v3 : 0.f);
        a3 += (t0 == 3 ? v0 : 0.f) + (t1 == 3 ? v1 : 0.f) + (t2 == 3 ? v2 : 0.f) + (t3 == 3 ? v3 : 0.f);
        a4 += (t0 == 4 ? v0 : 0.f) + (t1 == 4 ? v1 : 0.f) + (t2 == 4 ? v2 : 0.f) + (t3 == 4 ? v3 : 0.f);
    }
    for (; i < r1; ++i) {
        int p = eidx[i];
        float v = h[(size_t)(p & 0xFFFFF) * DD + lane];
        int t = p >> 20;
        a0 += (t == 0) ? v : 0.f;
        a1 += (t == 1) ? v : 0.f;
        a2 += (t == 2) ? v : 0.f;
        a3 += (t == 3) ? v : 0.f;
        a4 += (t == 4) ? v : 0.f;
    }
    float ic = invc[n];
    float vals[6];
    vals[0] = a0 * ic; vals[1] = a1 * ic; vals[2] = a2 * ic;
    vals[3] = a3 * ic; vals[4] = a4 * ic;
    vals[5] = h[(size_t)n * DD + lane];
    ushort_t* rh = scat_hi + (size_t)n * KK + lane;
    ushort_t* rl = scat_lo + (size_t)n * KK + lane;
#pragma unroll
    for (int t = 0; t < 6; ++t) {
        ushort_t hi = f2bf(vals[t]);
        ushort_t lo = f2bf(vals[t] - bf2f(hi));
        rh[t * DD] = hi;
        rl[t * DD] = lo;
    }
}

// Phase 2: h' = relu(scat @ Wcat + bias) via split-bf16 MFMA.
// Block = 4 waves; wave owns 16 rows x 64 cols; K=384 in 12 steps of 32.
// A frag: lane reads scat[n0 + (lane&15)][ks*32 + (lane>>4)*8 .. +7]
// B frag: lane reads WT[ct*16 + (lane&15)][ks*32 + (lane>>4)*8 .. +7]
// C/D:   col = lane&15, row = (lane>>4)*4 + reg   (m89-verified)
__global__ void __launch_bounds__(256) k_trans3(
        const ushort_t* __restrict__ scat_hi, const ushort_t* __restrict__ scat_lo,
        const ushort_t* __restrict__ wt_hi, const ushort_t* __restrict__ wt_lo,
        const float* __restrict__ bias, float* __restrict__ h) {
    int lane = threadIdx.x & 63, wave = threadIdx.x >> 6;
    int n0 = blockIdx.x * 64 + wave * 16;
    int row = lane & 15, kb = lane >> 4;
    const ushort_t* pa_hi = scat_hi + (size_t)(n0 + row) * KK + kb * 8;
    const ushort_t* pa_lo = scat_lo + (size_t)(n0 + row) * KK + kb * 8;
    const ushort_t* pb_hi = wt_hi + (size_t)row * KK + kb * 8;   // + ct*16*KK per tile
    const ushort_t* pb_lo = wt_lo + (size_t)row * KK + kb * 8;
    f32x4 acc[4];
#pragma unroll
    for (int ct = 0; ct < 4; ++ct) acc[ct] = (f32x4){0.f, 0.f, 0.f, 0.f};
#pragma unroll 2
    for (int ks = 0; ks < 12; ++ks) {
        bf16x8 ahi = *(const bf16x8*)(pa_hi + ks * 32);
        bf16x8 alo = *(const bf16x8*)(pa_lo + ks * 32);
#pragma unroll
        for (int ct = 0; ct < 4; ++ct) {
            bf16x8 bhi = *(const bf16x8*)(pb_hi + (size_t)ct * 16 * KK + ks * 32);
            bf16x8 blo = *(const bf16x8*)(pb_lo + (size_t)ct * 16 * KK + ks * 32);
            acc[ct] = __builtin_amdgcn_mfma_f32_16x16x32_bf16(ahi, bhi, acc[ct], 0, 0, 0);
            acc[ct] = __builtin_amdgcn_mfma_f32_16x16x32_bf16(ahi, blo, acc[ct], 0, 0, 0);
            acc[ct] = __builtin_amdgcn_mfma_f32_16x16x32_bf16(alo, bhi, acc[ct], 0, 0, 0);
        }
    }
#pragma unroll
    for (int ct = 0; ct < 4; ++ct) {
        float bv = bias[ct * 16 + row];
#pragma unroll
        for (int r = 0; r < 4; ++r) {
            int n = n0 + kb * 4 + r;
            if (n < NN)
                h[(size_t)n * DD + ct * 16 + row] = fmaxf(acc[ct][r] + bv, 0.f);
        }
    }
}

// LSTM cell: block per graph, 64 threads
__global__ void k_lstm(const float* __restrict__ qstar, float* __restrict__ hx,
                       float* __restrict__ cx, const float* __restrict__ wih,
                       const float* __restrict__ whh, const float* __restrict__ bih,
                       const float* __restrict__ bhh) {
    int g = blockIdx.x;
    int j = threadIdx.x;
    float acc[4];
#pragma unroll
    for (int q = 0; q < 4; ++q) acc[q] = bih[q * DD + j] + bhh[q * DD + j];
    const float4* q4 = (const float4*)(qstar + (size_t)g * 2 * DD);
#pragma unroll 8
    for (int k4 = 0; k4 < 32; ++k4) {
        float4 qv = q4[k4];
#pragma unroll
        for (int q = 0; q < 4; ++q) {
            float4 wv = ((const float4*)(wih + (size_t)(q * DD + j) * 2 * DD))[k4];
            acc[q] += qv.x * wv.x + qv.y * wv.y + qv.z * wv.z + qv.w * wv.w;
        }
    }
    const float4* h4 = (const float4*)(hx + (size_t)g * DD);
#pragma unroll 4
    for (int k4 = 0; k4 < 16; ++k4) {
        float4 hv = h4[k4];
#pragma unroll
        for (int q = 0; q < 4; ++q) {
            float4 wv = ((const float4*)(whh + (size_t)(q * DD + j) * DD))[k4];
            acc[q] += hv.x * wv.x + hv.y * wv.y + hv.z * wv.z + hv.w * wv.w;
        }
    }
    float c_old = cx[(size_t)g * DD + j];
    __syncthreads();
    float iv = sigmoidf_(acc[0]);
    float fv = sigmoidf_(acc[1]);
    float gv = tanhf(acc[2]);
    float ov = sigmoidf_(acc[3]);
    float c = fv * c_old + iv * gv;
    cx[(size_t)g * DD + j] = c;
    hx[(size_t)g * DD + j] = ov * tanhf(c);
}

// per-graph segment softmax + weighted sum; writes q_star = [q, r]
__global__ void k_attn(const float* __restrict__ h, const int* __restrict__ seg,
                       const float* __restrict__ hx, float* __restrict__ qstar,
                       float* __restrict__ esc) {
    int g = blockIdx.x;
    int lane = threadIdx.x & 63, wave = threadIdx.x >> 6;
    int s0 = seg[g], s1 = seg[g + 1];
    float q = hx[(size_t)g * DD + lane];
    __shared__ float lmax[4];
    __shared__ float lsum[4];
    __shared__ float lred[4][64];
    float mymax = -INFINITY;
    for (int n = s0 + wave; n < s1; n += 4) {
        float v = h[(size_t)n * DD + lane] * q;
#pragma unroll
        for (int off = 32; off >= 1; off >>= 1) v += __shfl_xor(v, off, 64);
        if (lane == 0) esc[n] = v;
        mymax = fmaxf(mymax, v);
    }
    if (lane == 0) lmax[wave] = mymax;
    __syncthreads();
    float m = fmaxf(fmaxf(lmax[0], lmax[1]), fmaxf(lmax[2], lmax[3]));
    float racc = 0.f, sacc = 0.f;
    for (int n = s0 + wave; n < s1; n += 4) {
        float a = expf(esc[n] - m);
        racc += a * h[(size_t)n * DD + lane];
        sacc += a;
    }
    lred[wave][lane] = racc;
    if (lane == 0) lsum[wave] = sacc;
    __syncthreads();
    if (wave == 0) {
        float r = lred[0][lane] + lred[1][lane] + lred[2][lane] + lred[3][lane];
        float s = lsum[0] + lsum[1] + lsum[2] + lsum[3];
        qstar[(size_t)g * 2 * DD + lane] = q;
        qstar[(size_t)g * 2 * DD + DD + lane] = (s > 0.f) ? (r / s) : 0.f;
    }
}

// out = relu(q_star @ lin1 + b1) @ lin2 + b2
__global__ void k_final(const float* __restrict__ qstar, const float* __restrict__ w1,
                        const float* __restrict__ b1, const float* __restrict__ w2,
                        const float* __restrict__ b2, float* __restrict__ out) {
    int g = blockIdx.x;
    int j = threadIdx.x;
    float a = b1[j];
    const float* qs = qstar + (size_t)g * 2 * DD;
#pragma unroll 16
    for (int k = 0; k < 2 * DD; ++k) a += qs[k] * w1[k * DD + j];
    float t = fmaxf(a, 0.f);
    __shared__ float ts[64];
    ts[j] = t;
    __syncthreads();
    if (j < 12) {
        float o = b2[j];
#pragma unroll 16
        for (int d = 0; d < DD; ++d) o += ts[d] * w2[d * 12 + j];
        out[(size_t)g * 12 + j] = o;
    }
}

extern "C" void kernel_launch(void* const* d_in, const int* in_sizes, int n_in,
                              void* d_out, int out_size, void* d_ws, size_t ws_size,
                              hipStream_t stream) {
    const float* x     = (const float*)d_in[0];
    const int*   ei    = (const int*)d_in[1];
    const int*   etype = (const int*)d_in[2];
    const int*   batch = (const int*)d_in[3];
    const float* l0w   = (const float*)d_in[4];
    const float* l0b   = (const float*)d_in[5];
    const float* basis = (const float*)d_in[6];
    const float* att   = (const float*)d_in[7];
    const float* root  = (const float*)d_in[8];
    const float* convb = (const float*)d_in[9];
    const float* wih   = (const float*)d_in[10];
    const float* whh   = (const float*)d_in[11];
    const float* bih   = (const float*)d_in[12];
    const float* bhh   = (const float*)d_in[13];
    const float* l1w   = (const float*)d_in[14];
    const float* l1b   = (const float*)d_in[15];
    const float* l2w   = (const float*)d_in[16];
    const float* l2b   = (const float*)d_in[17];
    const int* src = ei;
    const int* dst = ei + NE;
    float* out = (float*)d_out;

    char* ws = (char*)d_ws;
    size_t off = 0;
    auto alloc = [&](size_t bytes) {
        void* p = ws + off;
        off = (off + bytes + 255) & ~(size_t)255;
        return p;
    };
    ushort_t* wt_hi  = (ushort_t*)alloc((size_t)DD * KK * 2);
    ushort_t* wt_lo  = (ushort_t*)alloc((size_t)DD * KK * 2);
    float* h         = (float*)alloc((size_t)NN * DD * 4);
    ushort_t* scat_hi = (ushort_t*)alloc((size_t)NN * KK * 2);
    ushort_t* scat_lo = (ushort_t*)alloc((size_t)NN * KK * 2);
    int*   deg    = (int*)alloc((size_t)NN * 4);
    float* invc   = (float*)alloc((size_t)NN * 4);
    int*   part   = (int*)alloc((size_t)NN * 4);
    int*   bsum   = (int*)alloc((size_t)512 * 4);
    int*   rowptr = (int*)alloc((size_t)(NN + 1) * 4);
    int*   cur    = (int*)alloc((size_t)NN * 4);
    int*   eidx   = (int*)alloc((size_t)NE * 4);
    float* esc    = (float*)alloc((size_t)NN * 4);
    int*   seg    = (int*)alloc((size_t)(NG + 1) * 4);
    float* qstar  = (float*)alloc((size_t)NG * 2 * DD * 4);
    float* hx     = (float*)alloc((size_t)NG * DD * 4);
    float* cx     = (float*)alloc((size_t)NG * DD * 4);

    hipMemsetAsync(deg, 0, (size_t)NN * 4, stream);
    hipMemsetAsync(qstar, 0, (size_t)NG * 2 * DD * 4, stream);
    hipMemsetAsync(hx, 0, (size_t)NG * DD * 4, stream);
    hipMemsetAsync(cx, 0, (size_t)NG * DD * 4, stream);

    // CSR build
    k_cnt<<<(NE + 255) / 256, 256, 0, stream>>>(dst, deg);
    k_scan1<<<NB, 256, 0, stream>>>(deg, part, bsum);
    k_scan2<<<1, 512, 0, stream>>>(bsum);
    k_scan3<<<(NN + 255) / 256, 256, 0, stream>>>(part, bsum, deg, rowptr, invc);
    hipMemcpyAsync(cur, rowptr, (size_t)NN * 4, hipMemcpyDeviceToDevice, stream);
    k_fill<<<(NE + 255) / 256, 256, 0, stream>>>(src, dst, etype, cur, eidx);

    k_w2<<<(DD * KK + 255) / 256, 256, 0, stream>>>(att, basis, root, wt_hi, wt_lo);
    k_seg<<<(NG + 256) / 256, 256, 0, stream>>>(batch, seg);
    k_lin0<<<(NN + 255) / 256, 256, 0, stream>>>(x, l0w, l0b, h);

    for (int s = 0; s < 6; ++s) {
        k_gather3<<<(NN * 64 + 255) / 256, 256, 0, stream>>>(h, eidx, rowptr, invc,
                                                             scat_hi, scat_lo);
        k_trans3<<<(NN + 63) / 64, 256, 0, stream>>>(scat_hi, scat_lo, wt_hi, wt_lo,
                                                     convb, h);
    }

    for (int t = 0; t < 6; ++t) {
        k_lstm<<<NG, 64, 0, stream>>>(qstar, hx, cx, wih, whh, bih, bhh);
        k_attn<<<NG, 256, 0, stream>>>(h, seg, hx, qstar, esc);
    }

    k_final<<<NG, 64, 0, stream>>>(qstar, l1w, l1b, l2w, l2b, out);
}

// Round 7
// 1171.804 us; speedup vs baseline: 3.8803x; 1.2968x over previous
//
#include <hip/hip_runtime.h>
#include <hip/hip_bf16.h>
#include <math.h>

#define NN 100000
#define NE 800000
#define NG 2048
#define DD 64
#define NR 5
#define KK 384          // 6 * 64 (5 relations + root)
#define NB ((NN + 255) / 256)   // scan blocks = 391

typedef __attribute__((ext_vector_type(8))) short bf16x8;
typedef __attribute__((ext_vector_type(4))) float f32x4;
typedef unsigned short ushort_t;
typedef unsigned int uint_t;

static __device__ __forceinline__ float sigmoidf_(float x) { return 1.0f / (1.0f + expf(-x)); }

// round-to-nearest-even f32 -> bf16 (values known finite)
static __device__ __forceinline__ ushort_t f2bf(float f) {
    uint_t u = __float_as_uint(f);
    uint_t r = (u + 0x7FFFu + ((u >> 16) & 1u)) >> 16;
    return (ushort_t)r;
}
static __device__ __forceinline__ float bf2f(ushort_t b) {
    return __uint_as_float(((uint_t)b) << 16);
}

// WT[c][k] hi/lo bf16, c in [0,64), k = t*64+kd. t<5: sum_b att[t,b]*basis[b][kd][c]; t==5: root[kd][c].
__global__ void k_w2(const float* __restrict__ att, const float* __restrict__ basis,
                     const float* __restrict__ root, ushort_t* __restrict__ wt_hi,
                     ushort_t* __restrict__ wt_lo) {
    int i = blockIdx.x * blockDim.x + threadIdx.x;
    if (i >= DD * KK) return;
    int c = i / KK;
    int k = i % KK;
    int t = k >> 6;
    int kd = k & 63;
    float w;
    if (t < NR) {
        w = 0.f;
#pragma unroll
        for (int b = 0; b < NR; ++b) w += att[t * NR + b] * basis[(b * DD + kd) * DD + c];
    } else {
        w = root[kd * DD + c];
    }
    ushort_t hi = f2bf(w);
    ushort_t lo = f2bf(w - bf2f(hi));
    wt_hi[c * KK + k] = hi;
    wt_lo[c * KK + k] = lo;
}

// in-degree count (int)
__global__ void k_cnt(const int* __restrict__ dst, int* __restrict__ deg) {
    int e = blockIdx.x * blockDim.x + threadIdx.x;
    if (e < NE) atomicAdd(&deg[dst[e]], 1);
}

// block-local exclusive scan of deg; emits per-block totals
__global__ void k_scan1(const int* __restrict__ deg, int* __restrict__ part,
                        int* __restrict__ bsum) {
    __shared__ int s[256];
    int tid = threadIdx.x;
    int i = blockIdx.x * 256 + tid;
    int v = (i < NN) ? deg[i] : 0;
    s[tid] = v;
    __syncthreads();
    for (int off = 1; off < 256; off <<= 1) {
        int t = (tid >= off) ? s[tid - off] : 0;
        __syncthreads();
        s[tid] += t;
        __syncthreads();
    }
    if (i < NN) part[i] = s[tid] - v;
    if (tid == 255) bsum[blockIdx.x] = s[255];
}

__global__ void k_scan2(int* __restrict__ bsum) {
    __shared__ int s[512];
    int tid = threadIdx.x;
    int v = (tid < NB) ? bsum[tid] : 0;
    s[tid] = v;
    __syncthreads();
    for (int off = 1; off < 512; off <<= 1) {
        int t = (tid >= off) ? s[tid - off] : 0;
        __syncthreads();
        s[tid] += t;
        __syncthreads();
    }
    if (tid < NB) bsum[tid] = s[tid] - v;
}

__global__ void k_scan3(const int* __restrict__ part, const int* __restrict__ bsum,
                        const int* __restrict__ deg, int* __restrict__ rowptr,
                        float* __restrict__ invc) {
    int i = blockIdx.x * blockDim.x + threadIdx.x;
    if (i >= NN) return;
    rowptr[i] = part[i] + bsum[i >> 8];
    invc[i] = 1.0f / fmaxf((float)deg[i], 1.0f);
    if (i == 0) rowptr[NN] = NE;
}

// fill CSR: eidx[pos] = src | (type<<20)
__global__ void k_fill(const int* __restrict__ src, const int* __restrict__ dst,
                       const int* __restrict__ et, int* __restrict__ cur,
                       int* __restrict__ eidx) {
    int e = blockIdx.x * blockDim.x + threadIdx.x;
    if (e >= NE) return;
    int d = dst[e];
    int pos = atomicAdd(&cur[d], 1);
    eidx[pos] = src[e] | (et[e] << 20);
}

// segment starts: seg[g] = lower_bound(batch, g)
__global__ void k_seg(const int* __restrict__ batch, int* __restrict__ seg) {
    int g = blockIdx.x * blockDim.x + threadIdx.x;
    if (g > NG) return;
    int lo = 0, hi = NN;
    while (lo < hi) {
        int mid = (lo + hi) >> 1;
        if (batch[mid] < g) lo = mid + 1; else hi = mid;
    }
    seg[g] = lo;
}

// h = relu(x @ lin0_w + lin0_b)
__global__ void k_lin0(const float* __restrict__ x, const float* __restrict__ w,
                       const float* __restrict__ b, float* __restrict__ h) {
    int lane = threadIdx.x & 63, wave = threadIdx.x >> 6;
    float Wc[15];
#pragma unroll
    for (int k = 0; k < 15; ++k) Wc[k] = w[k * DD + lane];
    float bias = b[lane];
    int n0 = blockIdx.x * 256;
    int n1 = min(n0 + 256, NN);
    for (int n = n0 + wave; n < n1; n += 4) {
        int nu = __builtin_amdgcn_readfirstlane(n);
        const float* xr = x + (size_t)nu * 15;
        float a = bias;
#pragma unroll
        for (int k = 0; k < 15; ++k) a += xr[k] * Wc[k];
        h[(size_t)nu * DD + lane] = fmaxf(a, 0.f);
    }
}

// Fused RGCN step: hout = relu([mean-agg per rel | h] @ Wcat + bias).
// Block: 512 threads (8 waves), 32 dst nodes. 3125 blocks exactly (no tail).
// Phase A: wave w gathers nodes w*4..w*4+3 (lane = channel), per-relation sums,
//          split to bf16 hi/lo, store 32x384 tile in LDS.
// Phase B: wave w = (rg = w&1, ct = w>>2*... actually ct = w>>1): 16 rows x 16 cols,
//          12 k-steps x 3 split MFMAs. C/D: col=lane&15, row=(lane>>4)*4+reg.
__global__ void __launch_bounds__(512) k_conv(
        const float* __restrict__ h, const int* __restrict__ eidx,
        const int* __restrict__ rowptr, const float* __restrict__ invc,
        const ushort_t* __restrict__ wt_hi, const ushort_t* __restrict__ wt_lo,
        const float* __restrict__ bias, float* __restrict__ hout) {
    __shared__ ushort_t lhi[32][392];   // row stride 784B (16B-aligned)
    __shared__ ushort_t llo[32][392];
    int tid = threadIdx.x;
    int lane = tid & 63, w = tid >> 6;
    int n0 = blockIdx.x * 32;

    // ---- Phase A: gather 4 nodes per wave ----
    for (int i = 0; i < 4; ++i) {
        int row = w * 4 + i;
        int n = __builtin_amdgcn_readfirstlane(n0 + row);
        int r0 = rowptr[n], r1 = rowptr[n + 1];
        float a0 = 0.f, a1 = 0.f, a2 = 0.f, a3 = 0.f, a4 = 0.f;
        int e = r0;
        for (; e + 4 <= r1; e += 4) {
            int p0 = eidx[e + 0], p1 = eidx[e + 1], p2 = eidx[e + 2], p3 = eidx[e + 3];
            float v0 = h[(size_t)(p0 & 0xFFFFF) * DD + lane];
            float v1 = h[(size_t)(p1 & 0xFFFFF) * DD + lane];
            float v2 = h[(size_t)(p2 & 0xFFFFF) * DD + lane];
            float v3 = h[(size_t)(p3 & 0xFFFFF) * DD + lane];
            int t0 = p0 >> 20, t1 = p1 >> 20, t2 = p2 >> 20, t3 = p3 >> 20;
            a0 += (t0 == 0 ? v0 : 0.f) + (t1 == 0 ? v1 : 0.f) + (t2 == 0 ? v2 : 0.f) + (t3 == 0 ? v3 : 0.f);
            a1 += (t0 == 1 ? v0 : 0.f) + (t1 == 1 ? v1 : 0.f) + (t2 == 1 ? v2 : 0.f) + (t3 == 1 ? v3 : 0.f);
            a2 += (t0 == 2 ? v0 : 0.f) + (t1 == 2 ? v1 : 0.f) + (t2 == 2 ? v2 : 0.f) + (t3 == 2 ? v3 : 0.f);
            a3 += (t0 == 3 ? v0 : 0.f) + (t1 == 3 ? v1 : 0.f) + (t2 == 3 ? v2 : 0.f) + (t3 == 3 ? v3 : 0.f);
            a4 += (t0 == 4 ? v0 : 0.f) + (t1 == 4 ? v1 : 0.f) + (t2 == 4 ? v2 : 0.f) + (t3 == 4 ? v3 : 0.f);
        }
        for (; e < r1; ++e) {
            int p = eidx[e];
            float v = h[(size_t)(p & 0xFFFFF) * DD + lane];
            int t = p >> 20;
            a0 += (t == 0) ? v : 0.f;
            a1 += (t == 1) ? v : 0.f;
            a2 += (t == 2) ? v : 0.f;
            a3 += (t == 3) ? v : 0.f;
            a4 += (t == 4) ? v : 0.f;
        }
        float ic = invc[n];
        float vals[6];
        vals[0] = a0 * ic; vals[1] = a1 * ic; vals[2] = a2 * ic;
        vals[3] = a3 * ic; vals[4] = a4 * ic;
        vals[5] = h[(size_t)n * DD + lane];
#pragma unroll
        for (int t = 0; t < 6; ++t) {
            ushort_t hi = f2bf(vals[t]);
            ushort_t lo = f2bf(vals[t] - bf2f(hi));
            lhi[row][t * 64 + lane] = hi;
            llo[row][t * 64 + lane] = lo;
        }
    }
    __syncthreads();

    // ---- Phase B: split-bf16 MFMA from LDS ----
    int rg = w & 1;          // row group: LDS rows rg*16..+15
    int ct = w >> 1;         // col tile:  output cols ct*16..+15
    int crow = lane & 15, kb = lane >> 4;
    const ushort_t* pbh = wt_hi + (size_t)(ct * 16 + crow) * KK + kb * 8;
    const ushort_t* pbl = wt_lo + (size_t)(ct * 16 + crow) * KK + kb * 8;
    f32x4 acc = (f32x4){0.f, 0.f, 0.f, 0.f};
#pragma unroll 3
    for (int ks = 0; ks < 12; ++ks) {
        bf16x8 ahi = *(const bf16x8*)&lhi[rg * 16 + crow][ks * 32 + kb * 8];
        bf16x8 alo = *(const bf16x8*)&llo[rg * 16 + crow][ks * 32 + kb * 8];
        bf16x8 bhi = *(const bf16x8*)(pbh + ks * 32);
        bf16x8 blo = *(const bf16x8*)(pbl + ks * 32);
        acc = __builtin_amdgcn_mfma_f32_16x16x32_bf16(ahi, bhi, acc, 0, 0, 0);
        acc = __builtin_amdgcn_mfma_f32_16x16x32_bf16(ahi, blo, acc, 0, 0, 0);
        acc = __builtin_amdgcn_mfma_f32_16x16x32_bf16(alo, bhi, acc, 0, 0, 0);
    }
    float bv = bias[ct * 16 + crow];
#pragma unroll
    for (int r = 0; r < 4; ++r) {
        int n = n0 + rg * 16 + kb * 4 + r;
        hout[(size_t)n * DD + ct * 16 + crow] = fmaxf(acc[r] + bv, 0.f);
    }
}

// Fused set2set step: LSTM cell + segment softmax attention. Block per graph, 256 thr.
__global__ void k_s2s(const float* __restrict__ h, const int* __restrict__ seg,
                      const float* __restrict__ wih, const float* __restrict__ whh,
                      const float* __restrict__ bih, const float* __restrict__ bhh,
                      float* __restrict__ hxg, float* __restrict__ cx,
                      float* __restrict__ qstar, float* __restrict__ esc) {
    int g = blockIdx.x;
    int tid = threadIdx.x;
    int lane = tid & 63, wave = tid >> 6;
    __shared__ float gates_f[256];
    __shared__ float hs[64];
    __shared__ float lmax[4];
    __shared__ float lsum[4];
    __shared__ float lred[4][64];

    // LSTM: thread tid computes gate row tid (row = q*64 + c)
    {
        float acc = bih[tid] + bhh[tid];
        const float4* q4 = (const float4*)(qstar + (size_t)g * 2 * DD);
        const float4* w4 = (const float4*)(wih + (size_t)tid * 2 * DD);
#pragma unroll 8
        for (int k4 = 0; k4 < 32; ++k4) {
            float4 qv = q4[k4], wv = w4[k4];
            acc += qv.x * wv.x + qv.y * wv.y + qv.z * wv.z + qv.w * wv.w;
        }
        const float4* hx4 = (const float4*)(hxg + (size_t)g * DD);
        const float4* wh4 = (const float4*)(whh + (size_t)tid * DD);
#pragma unroll 4
        for (int k4 = 0; k4 < 16; ++k4) {
            float4 hv = hx4[k4], wv = wh4[k4];
            acc += hv.x * wv.x + hv.y * wv.y + hv.z * wv.z + hv.w * wv.w;
        }
        gates_f[tid] = acc;
    }
    __syncthreads();
    if (tid < 64) {
        int c = tid;
        float iv = sigmoidf_(gates_f[c]);
        float fv = sigmoidf_(gates_f[64 + c]);
        float gv = tanhf(gates_f[128 + c]);
        float ov = sigmoidf_(gates_f[192 + c]);
        float cc = fv * cx[(size_t)g * DD + c] + iv * gv;
        float hh = ov * tanhf(cc);
        cx[(size_t)g * DD + c] = cc;
        hxg[(size_t)g * DD + c] = hh;
        hs[c] = hh;
    }
    __syncthreads();

    // attention over the graph's segment
    int s0 = seg[g], s1 = seg[g + 1];
    float q = hs[lane];
    float mymax = -INFINITY;
    for (int n = s0 + wave; n < s1; n += 4) {
        float v = h[(size_t)n * DD + lane] * q;
#pragma unroll
        for (int off = 32; off >= 1; off >>= 1) v += __shfl_xor(v, off, 64);
        if (lane == 0) esc[n] = v;
        mymax = fmaxf(mymax, v);
    }
    if (lane == 0) lmax[wave] = mymax;
    __syncthreads();
    float m = fmaxf(fmaxf(lmax[0], lmax[1]), fmaxf(lmax[2], lmax[3]));
    float racc = 0.f, sacc = 0.f;
    for (int n = s0 + wave; n < s1; n += 4) {
        float a = expf(esc[n] - m);
        racc += a * h[(size_t)n * DD + lane];
        sacc += a;
    }
    lred[wave][lane] = racc;
    if (lane == 0) lsum[wave] = sacc;
    __syncthreads();
    if (wave == 0) {
        float r = lred[0][lane] + lred[1][lane] + lred[2][lane] + lred[3][lane];
        float s = lsum[0] + lsum[1] + lsum[2] + lsum[3];
        qstar[(size_t)g * 2 * DD + lane] = q;
        qstar[(size_t)g * 2 * DD + DD + lane] = (s > 0.f) ? (r / s) : 0.f;
    }
}

// out = relu(q_star @ lin1 + b1) @ lin2 + b2
__global__ void k_final(const float* __restrict__ qstar, const float* __restrict__ w1,
                        const float* __restrict__ b1, const float* __restrict__ w2,
                        const float* __restrict__ b2, float* __restrict__ out) {
    int g = blockIdx.x;
    int j = threadIdx.x;
    float a = b1[j];
    const float* qs = qstar + (size_t)g * 2 * DD;
#pragma unroll 16
    for (int k = 0; k < 2 * DD; ++k) a += qs[k] * w1[k * DD + j];
    float t = fmaxf(a, 0.f);
    __shared__ float ts[64];
    ts[j] = t;
    __syncthreads();
    if (j < 12) {
        float o = b2[j];
#pragma unroll 16
        for (int d = 0; d < DD; ++d) o += ts[d] * w2[d * 12 + j];
        out[(size_t)g * 12 + j] = o;
    }
}

extern "C" void kernel_launch(void* const* d_in, const int* in_sizes, int n_in,
                              void* d_out, int out_size, void* d_ws, size_t ws_size,
                              hipStream_t stream) {
    const float* x     = (const float*)d_in[0];
    const int*   ei    = (const int*)d_in[1];
    const int*   etype = (const int*)d_in[2];
    const int*   batch = (const int*)d_in[3];
    const float* l0w   = (const float*)d_in[4];
    const float* l0b   = (const float*)d_in[5];
    const float* basis = (const float*)d_in[6];
    const float* att   = (const float*)d_in[7];
    const float* root  = (const float*)d_in[8];
    const float* convb = (const float*)d_in[9];
    const float* wih   = (const float*)d_in[10];
    const float* whh   = (const float*)d_in[11];
    const float* bih   = (const float*)d_in[12];
    const float* bhh   = (const float*)d_in[13];
    const float* l1w   = (const float*)d_in[14];
    const float* l1b   = (const float*)d_in[15];
    const float* l2w   = (const float*)d_in[16];
    const float* l2b   = (const float*)d_in[17];
    const int* src = ei;
    const int* dst = ei + NE;
    float* out = (float*)d_out;

    char* ws = (char*)d_ws;
    size_t off = 0;
    auto alloc = [&](size_t bytes) {
        void* p = ws + off;
        off = (off + bytes + 255) & ~(size_t)255;
        return p;
    };
    ushort_t* wt_hi = (ushort_t*)alloc((size_t)DD * KK * 2);
    ushort_t* wt_lo = (ushort_t*)alloc((size_t)DD * KK * 2);
    float* h_a    = (float*)alloc((size_t)NN * DD * 4);
    float* h_b    = (float*)alloc((size_t)NN * DD * 4);
    int*   deg    = (int*)alloc((size_t)NN * 4);
    float* invc   = (float*)alloc((size_t)NN * 4);
    int*   part   = (int*)alloc((size_t)NN * 4);
    int*   bsum   = (int*)alloc((size_t)512 * 4);
    int*   rowptr = (int*)alloc((size_t)(NN + 1) * 4);
    int*   cur    = (int*)alloc((size_t)NN * 4);
    int*   eidx   = (int*)alloc((size_t)NE * 4);
    float* esc    = (float*)alloc((size_t)NN * 4);
    int*   seg    = (int*)alloc((size_t)(NG + 1) * 4);
    float* qstar  = (float*)alloc((size_t)NG * 2 * DD * 4);
    float* hx     = (float*)alloc((size_t)NG * DD * 4);
    float* cx     = (float*)alloc((size_t)NG * DD * 4);

    hipMemsetAsync(deg, 0, (size_t)NN * 4, stream);
    hipMemsetAsync(qstar, 0, (size_t)NG * 2 * DD * 4, stream);
    hipMemsetAsync(hx, 0, (size_t)NG * DD * 4, stream);
    hipMemsetAsync(cx, 0, (size_t)NG * DD * 4, stream);

    // CSR build
    k_cnt<<<(NE + 255) / 256, 256, 0, stream>>>(dst, deg);
    k_scan1<<<NB, 256, 0, stream>>>(deg, part, bsum);
    k_scan2<<<1, 512, 0, stream>>>(bsum);
    k_scan3<<<(NN + 255) / 256, 256, 0, stream>>>(part, bsum, deg, rowptr, invc);
    hipMemcpyAsync(cur, rowptr, (size_t)NN * 4, hipMemcpyDeviceToDevice, stream);
    k_fill<<<(NE + 255) / 256, 256, 0, stream>>>(src, dst, etype, cur, eidx);

    k_w2<<<(DD * KK + 255) / 256, 256, 0, stream>>>(att, basis, root, wt_hi, wt_lo);
    k_seg<<<(NG + 256) / 256, 256, 0, stream>>>(batch, seg);
    k_lin0<<<(NN + 255) / 256, 256, 0, stream>>>(x, l0w, l0b, h_a);

    // 6 RGCN steps, ping-pong h_a <-> h_b (even count: final state in h_a)
    for (int s = 0; s < 6; ++s) {
        const float* hin = (s & 1) ? h_b : h_a;
        float* hout      = (s & 1) ? h_a : h_b;
        k_conv<<<NN / 32, 512, 0, stream>>>(hin, eidx, rowptr, invc,
                                            wt_hi, wt_lo, convb, hout);
    }
    const float* hfin = h_a;

    for (int t = 0; t < 6; ++t) {
        k_s2s<<<NG, 256, 0, stream>>>(hfin, seg, wih, whh, bih, bhh, hx, cx, qstar, esc);
    }

    k_final<<<NG, 64, 0, stream>>>(qstar, l1w, l1b, l2w, l2b, out);
}